// Round 11
// baseline (247.577 us; speedup 1.0000x reference)
//
#include <hip/hip_runtime.h>

// BaggingMaxPool: out[d] = mean_k( max_{r in indices[k,:]} inp[r][d] )
// N=1024 rows, D=100000 cols, K=20 rounds, SELECT_N=256.
//
// Round-11: persistent blocks (1/CU) + intra-block T14 async staging over a
// ping-pong LDS tile, so HBM fetch of tile t+1 overlaps DS/VALU compute of
// tile t (round 9's 2 phases ran serial: resident blocks start in lockstep;
// round 10's wave-specialization starved the DS pipe at 1 consumer
// wave/SIMD). All 4 waves both compute and prefetch.
//   per tile: [issue 16x global float4 -> regs] [compute buf[cur]]
//             [barrier] [ds_write regs -> buf[cur^1]; finalize -> out]
//             [barrier]
// Reduce over the 16 entry-groups: strides 4,8 as DPP row_shr funnels
// (VALU pipe, result valid in lanes 12..15 of each 16-lane row) +
// shfl_xor 16/32 (DS) -> halves the DS-pipe reduce cost vs round 9.
// idx preload (u16, [k][g][j] transposed) once per ~24 tiles.
// LDS: 2x64KB tile + 10.25KB idx + 256B wpart = ~139KB -> 1 block/CU.

#define N_ROWS   1024
#define D_COLS   100000
#define K_ROUNDS 20
#define SEL_N    256
#define NIDX     (K_ROUNDS * SEL_N)         // 5120
#define CPB      16                         // cols per tile
#define NT       (D_COLS / CPB)             // 6250 tiles (exact)
#define BLOCK    256
#define GRID     256
#define WAVES    4
#define RNDS_PW  (K_ROUNDS / WAVES)         // 5
#define NEG_INF  (-3.402823466e+38f)

// acc = max(acc, lane_shifted_down_by_N(acc)) within each 16-lane row.
// Lanes with (lane%16) < N keep old=self (bound_ctrl=false) -> no-op.
template<int CTRL>
__device__ __forceinline__ float dpp_shr_max(float x) {
    const int xi = __float_as_int(x);
    const int sh = __builtin_amdgcn_update_dpp(xi, xi, CTRL, 0xF, 0xF, false);
    return fmaxf(x, __int_as_float(sh));
}
#define ROW_SHR4 0x114
#define ROW_SHR8 0x118

__global__ __launch_bounds__(BLOCK, 1) void bagmax_kernel(
    const float* __restrict__ inp,
    const int*   __restrict__ indices,
    float*       __restrict__ out)
{
    __shared__ float tile[2][N_ROWS * CPB];                 // 128 KB
    __shared__ __align__(16) unsigned short sidx[NIDX];     // 10.25 KB
    __shared__ float wpart[WAVES][CPB];                     // 256 B

    const int tid  = threadIdx.x;
    const int lane = tid & 63;
    const int wave = tid >> 6;

    // XCD-chunk swizzle: block b owns col-chunks swz + t*GRID with
    // swz = (b&7)*32 + (b>>3): each XCD's 32 CUs get 32 CONSECUTIVE chunks,
    // so adjacent 64B col segments share L2 cache lines within one XCD.
    const int b   = blockIdx.x;
    const int swz = (b & 7) * 32 + (b >> 3);
    const int cnt = (NT - swz + GRID - 1) / GRID;           // 24 or 25 tiles

    // ---- idx preload: coalesced, u16 transposed to [k][g][j] ----
    for (int i = tid; i < NIDX; i += BLOCK) {
        const int p   = i & 255;
        const int dst = (i & ~255) | ((p & 15) << 4) | (p >> 4);
        sidx[dst] = (unsigned short)indices[i];
    }

    const int ro = tid >> 2;            // 0..63
    const int c4 = (tid & 3) * 4;       // 0,4,8,12

    // ---- prologue: stage tile 0 into buf0 ----
    {
        const float* gp = inp + (size_t)ro * D_COLS + swz * CPB + c4;
        float4 v[16];
        #pragma unroll
        for (int it = 0; it < 16; ++it)
            v[it] = *reinterpret_cast<const float4*>(gp + (size_t)it * 64 * D_COLS);
        #pragma unroll
        for (int it = 0; it < 16; ++it)
            *reinterpret_cast<float4*>(&tile[0][(it * 64 + ro) * CPB + c4]) = v[it];
    }
    __syncthreads();

    const int g = lane >> 2;            // entry group 0..15
    const int u = lane & 3;             // col unit (cols u*4..u*4+3)

    #pragma unroll 1
    for (int i = 0; i < cnt; ++i) {
        const int cur = i & 1;
        const bool havenext = (i + 1 < cnt);

        // ---- T14 issue-early: global loads for tile i+1 (hide under compute) ----
        float4 pf[16];
        if (havenext) {
            const int ncol = (swz + (i + 1) * GRID) * CPB;
            const float* gp = inp + (size_t)ro * D_COLS + ncol + c4;
            #pragma unroll
            for (int it = 0; it < 16; ++it)
                pf[it] = *reinterpret_cast<const float4*>(gp + (size_t)it * 64 * D_COLS);
        }

        // ---- round-major compute on buf[cur] ----
        const float* tb = &tile[cur][0];
        float4 rsum = make_float4(0.f, 0.f, 0.f, 0.f);
        #pragma unroll
        for (int kk = 0; kk < RNDS_PW; ++kk) {
            const int k = wave * RNDS_PW + kk;

            const uint4* sp = reinterpret_cast<const uint4*>(&sidx[k * SEL_N + g * 16]);
            const uint4 w0 = sp[0];
            const uint4 w1 = sp[1];
            unsigned int e[16];
            e[0]  = w0.x & 0xFFFFu; e[1]  = w0.x >> 16;
            e[2]  = w0.y & 0xFFFFu; e[3]  = w0.y >> 16;
            e[4]  = w0.z & 0xFFFFu; e[5]  = w0.z >> 16;
            e[6]  = w0.w & 0xFFFFu; e[7]  = w0.w >> 16;
            e[8]  = w1.x & 0xFFFFu; e[9]  = w1.x >> 16;
            e[10] = w1.y & 0xFFFFu; e[11] = w1.y >> 16;
            e[12] = w1.z & 0xFFFFu; e[13] = w1.z >> 16;
            e[14] = w1.w & 0xFFFFu; e[15] = w1.w >> 16;

            float4 a0 = make_float4(NEG_INF, NEG_INF, NEG_INF, NEG_INF);
            float4 a1 = a0;
            #pragma unroll
            for (int j = 0; j < 16; j += 2) {
                const float4 v0 = *reinterpret_cast<const float4*>(&tb[e[j]     * CPB + u * 4]);
                const float4 v1 = *reinterpret_cast<const float4*>(&tb[e[j + 1] * CPB + u * 4]);
                a0.x = fmaxf(a0.x, v0.x); a0.y = fmaxf(a0.y, v0.y);
                a0.z = fmaxf(a0.z, v0.z); a0.w = fmaxf(a0.w, v0.w);
                a1.x = fmaxf(a1.x, v1.x); a1.y = fmaxf(a1.y, v1.y);
                a1.z = fmaxf(a1.z, v1.z); a1.w = fmaxf(a1.w, v1.w);
            }
            float4 acc;
            acc.x = fmaxf(a0.x, a1.x); acc.y = fmaxf(a0.y, a1.y);
            acc.z = fmaxf(a0.z, a1.z); acc.w = fmaxf(a0.w, a1.w);

            // strides 4,8: DPP funnel (VALU) -> valid in lanes 12..15 of each row
            acc.x = dpp_shr_max<ROW_SHR4>(acc.x); acc.y = dpp_shr_max<ROW_SHR4>(acc.y);
            acc.z = dpp_shr_max<ROW_SHR4>(acc.z); acc.w = dpp_shr_max<ROW_SHR4>(acc.w);
            acc.x = dpp_shr_max<ROW_SHR8>(acc.x); acc.y = dpp_shr_max<ROW_SHR8>(acc.y);
            acc.z = dpp_shr_max<ROW_SHR8>(acc.z); acc.w = dpp_shr_max<ROW_SHR8>(acc.w);
            // strides 16,32: cross-row (DS pipe)
            acc.x = fmaxf(acc.x, __shfl_xor(acc.x, 16, 64));
            acc.y = fmaxf(acc.y, __shfl_xor(acc.y, 16, 64));
            acc.z = fmaxf(acc.z, __shfl_xor(acc.z, 16, 64));
            acc.w = fmaxf(acc.w, __shfl_xor(acc.w, 16, 64));
            acc.x = fmaxf(acc.x, __shfl_xor(acc.x, 32, 64));
            acc.y = fmaxf(acc.y, __shfl_xor(acc.y, 32, 64));
            acc.z = fmaxf(acc.z, __shfl_xor(acc.z, 32, 64));
            acc.w = fmaxf(acc.w, __shfl_xor(acc.w, 32, 64));

            rsum.x += acc.x; rsum.y += acc.y; rsum.z += acc.z; rsum.w += acc.w;
        }
        if (g == 3)   // lanes 12..15 hold the full reduction; u = lane&3
            *reinterpret_cast<float4*>(&wpart[wave][u * 4]) = rsum;

        __syncthreads();   // wpart ready; buf[cur^1] reads (iter i-1) long done

        // ---- write prefetched tile into the other buffer ----
        if (havenext) {
            float* tbn = &tile[cur ^ 1][0];
            #pragma unroll
            for (int it = 0; it < 16; ++it)
                *reinterpret_cast<float4*>(&tbn[(it * 64 + ro) * CPB + c4]) = pf[it];
        }
        // ---- finalize tile i ----
        if (tid < CPB) {
            const int col = (swz + i * GRID) * CPB + tid;
            const float s = wpart[0][tid] + wpart[1][tid] + wpart[2][tid] + wpart[3][tid];
            out[col] = s * (1.0f / (float)K_ROUNDS);
        }
        __syncthreads();   // buf writes visible + wpart reads done before next iter
    }
}

extern "C" void kernel_launch(void* const* d_in, const int* in_sizes, int n_in,
                              void* d_out, int out_size, void* d_ws, size_t ws_size,
                              hipStream_t stream) {
    const float* inp     = (const float*)d_in[0];
    const int*   indices = (const int*)d_in[1];
    float*       out     = (float*)d_out;

    bagmax_kernel<<<GRID, BLOCK, 0, stream>>>(inp, indices, out);
}

// Round 12
// 146.724 us; speedup vs baseline: 1.6874x; 1.6874x over previous
//
#include <hip/hip_runtime.h>

// BaggingMaxPool: out[d] = mean_k( max_{r in indices[k,:]} inp[r][d] )
// N=1024 rows, D=100000 cols, K=20 rounds, SELECT_N=256.
//
// Round-12: persistent blocks (1/CU), ping-pong LDS tile, staging via
// __builtin_amdgcn_global_load_lds width=16 (async, ZERO VGPR cost).
// Round 11 failed because pf[16] register prefetch (64 VGPRs live across
// compute) spilled to scratch (VGPR=132 counter). gload_lds removes the
// register footprint and the ds_write phase; ONE barrier per tile.
//   per tile i: [issue 16x gload_lds -> buf^1 for tile i+1]
//               [finalize tile i-1 from wpart^1] [compute buf[cur]]
//               [s_waitcnt vmcnt(0)] [__syncthreads]
// Staging layout matches the HW constraint exactly: LDS dest wave-uniform
// base + lane*16B; global source per-lane (row = it*64+wave*16+(lane>>2),
// cols (lane&3)*4). Compute = round-9 proven body + DPP row_shr funnel
// (strides 4,8 on VALU pipe; verified correct in round 11) + shfl 16/32.
// LDS: 2x64KB tile + 10.25KB idx + 512B wpart = ~139KB -> 1 block/CU.

#define N_ROWS   1024
#define D_COLS   100000
#define K_ROUNDS 20
#define SEL_N    256
#define NIDX     (K_ROUNDS * SEL_N)         // 5120
#define CPB      16                         // cols per tile
#define NT       (D_COLS / CPB)             // 6250 tiles (exact)
#define BLOCK    256
#define GRID     256
#define WAVES    4
#define RNDS_PW  (K_ROUNDS / WAVES)         // 5
#define NEG_INF  (-3.402823466e+38f)

// acc = max(acc, lane_shifted_down_by_N(acc)) within each 16-lane row.
template<int CTRL>
__device__ __forceinline__ float dpp_shr_max(float x) {
    const int xi = __float_as_int(x);
    const int sh = __builtin_amdgcn_update_dpp(xi, xi, CTRL, 0xF, 0xF, false);
    return fmaxf(x, __int_as_float(sh));
}
#define ROW_SHR4 0x114
#define ROW_SHR8 0x118

__device__ __forceinline__ void async_cp16(const float* g, float* l) {
    __builtin_amdgcn_global_load_lds(
        (const __attribute__((address_space(1))) unsigned int*)g,
        (__attribute__((address_space(3))) unsigned int*)l,
        16, 0, 0);
}

// Issue one tile's staging (async). LDS dest is wave-uniform; HW adds lane*16B.
__device__ __forceinline__ void stage_tile(const float* __restrict__ inp,
                                           float* __restrict__ buf,
                                           int colbase, int wave, int lane) {
    const int rsub = lane >> 2;             // 0..15
    const int c4   = (lane & 3) * 4;        // 0,4,8,12
    #pragma unroll
    for (int it = 0; it < 16; ++it) {
        const int row = it * 64 + wave * 16 + rsub;
        const float* g = inp + (size_t)row * D_COLS + colbase + c4;   // per-lane
        float* l = &buf[(it * 64 + wave * 16) * CPB];                 // uniform
        async_cp16(g, l);
    }
}

__global__ __launch_bounds__(BLOCK, 1) void bagmax_kernel(
    const float* __restrict__ inp,
    const int*   __restrict__ indices,
    float*       __restrict__ out)
{
    __shared__ float tile[2][N_ROWS * CPB];                 // 128 KB
    __shared__ __align__(16) unsigned short sidx[NIDX];     // 10.25 KB
    __shared__ float wpart[2][WAVES][CPB];                  // 512 B

    const int tid  = threadIdx.x;
    const int lane = tid & 63;
    const int wave = tid >> 6;

    // XCD-chunk swizzle: each XCD's 32 CUs own 32 consecutive col-chunks.
    const int b   = blockIdx.x;
    const int swz = (b & 7) * 32 + (b >> 3);
    const int cnt = (NT - swz + GRID - 1) / GRID;           // 24 or 25 tiles

    // ---- idx preload: coalesced, u16 transposed to [k][g][j] ----
    for (int i = tid; i < NIDX; i += BLOCK) {
        const int p   = i & 255;
        const int dst = (i & ~255) | ((p & 15) << 4) | (p >> 4);
        sidx[dst] = (unsigned short)indices[i];
    }

    // ---- prologue: issue stage of tile 0 ----
    stage_tile(inp, &tile[0][0], swz * CPB, wave, lane);
    asm volatile("s_waitcnt vmcnt(0)" ::: "memory");
    __syncthreads();

    const int g = lane >> 2;            // entry group 0..15
    const int u = lane & 3;             // col unit (cols u*4..u*4+3)

    #pragma unroll 1
    for (int i = 0; i < cnt; ++i) {
        const int cur = i & 1;

        // ---- issue async staging of tile i+1 into the other buffer ----
        if (i + 1 < cnt)
            stage_tile(inp, &tile[cur ^ 1][0], (swz + (i + 1) * GRID) * CPB, wave, lane);

        // ---- finalize tile i-1 (wpart other parity; stable since last barrier) ----
        if (i > 0 && tid < CPB) {
            const float* wp0 = wpart[cur ^ 1][0];
            const float s = wp0[tid] + wpart[cur ^ 1][1][tid]
                          + wpart[cur ^ 1][2][tid] + wpart[cur ^ 1][3][tid];
            out[(swz + (i - 1) * GRID) * CPB + tid] = s * (1.0f / (float)K_ROUNDS);
        }

        // ---- round-major compute on buf[cur] ----
        const float* tb = &tile[cur][0];
        float4 rsum = make_float4(0.f, 0.f, 0.f, 0.f);
        #pragma unroll
        for (int kk = 0; kk < RNDS_PW; ++kk) {
            const int k = wave * RNDS_PW + kk;

            const uint4* sp = reinterpret_cast<const uint4*>(&sidx[k * SEL_N + g * 16]);
            const uint4 w0 = sp[0];
            const uint4 w1 = sp[1];
            unsigned int e[16];
            e[0]  = w0.x & 0xFFFFu; e[1]  = w0.x >> 16;
            e[2]  = w0.y & 0xFFFFu; e[3]  = w0.y >> 16;
            e[4]  = w0.z & 0xFFFFu; e[5]  = w0.z >> 16;
            e[6]  = w0.w & 0xFFFFu; e[7]  = w0.w >> 16;
            e[8]  = w1.x & 0xFFFFu; e[9]  = w1.x >> 16;
            e[10] = w1.y & 0xFFFFu; e[11] = w1.y >> 16;
            e[12] = w1.z & 0xFFFFu; e[13] = w1.z >> 16;
            e[14] = w1.w & 0xFFFFu; e[15] = w1.w >> 16;

            float4 a0 = make_float4(NEG_INF, NEG_INF, NEG_INF, NEG_INF);
            float4 a1 = a0;
            #pragma unroll
            for (int j = 0; j < 16; j += 2) {
                const float4 v0 = *reinterpret_cast<const float4*>(&tb[e[j]     * CPB + u * 4]);
                const float4 v1 = *reinterpret_cast<const float4*>(&tb[e[j + 1] * CPB + u * 4]);
                a0.x = fmaxf(a0.x, v0.x); a0.y = fmaxf(a0.y, v0.y);
                a0.z = fmaxf(a0.z, v0.z); a0.w = fmaxf(a0.w, v0.w);
                a1.x = fmaxf(a1.x, v1.x); a1.y = fmaxf(a1.y, v1.y);
                a1.z = fmaxf(a1.z, v1.z); a1.w = fmaxf(a1.w, v1.w);
            }
            float4 acc;
            acc.x = fmaxf(a0.x, a1.x); acc.y = fmaxf(a0.y, a1.y);
            acc.z = fmaxf(a0.z, a1.z); acc.w = fmaxf(a0.w, a1.w);

            // strides 4,8: DPP funnel (VALU pipe) -> valid in lanes 12..15/row
            acc.x = dpp_shr_max<ROW_SHR4>(acc.x); acc.y = dpp_shr_max<ROW_SHR4>(acc.y);
            acc.z = dpp_shr_max<ROW_SHR4>(acc.z); acc.w = dpp_shr_max<ROW_SHR4>(acc.w);
            acc.x = dpp_shr_max<ROW_SHR8>(acc.x); acc.y = dpp_shr_max<ROW_SHR8>(acc.y);
            acc.z = dpp_shr_max<ROW_SHR8>(acc.z); acc.w = dpp_shr_max<ROW_SHR8>(acc.w);
            // strides 16,32: cross-row (DS pipe)
            acc.x = fmaxf(acc.x, __shfl_xor(acc.x, 16, 64));
            acc.y = fmaxf(acc.y, __shfl_xor(acc.y, 16, 64));
            acc.z = fmaxf(acc.z, __shfl_xor(acc.z, 16, 64));
            acc.w = fmaxf(acc.w, __shfl_xor(acc.w, 16, 64));
            acc.x = fmaxf(acc.x, __shfl_xor(acc.x, 32, 64));
            acc.y = fmaxf(acc.y, __shfl_xor(acc.y, 32, 64));
            acc.z = fmaxf(acc.z, __shfl_xor(acc.z, 32, 64));
            acc.w = fmaxf(acc.w, __shfl_xor(acc.w, 32, 64));

            rsum.x += acc.x; rsum.y += acc.y; rsum.z += acc.z; rsum.w += acc.w;
        }
        if (g == 3)   // lanes 12..15 hold the full reduction
            *reinterpret_cast<float4*>(&wpart[cur][wave][u * 4]) = rsum;

        // ---- drain prefetch + one barrier per tile ----
        asm volatile("s_waitcnt vmcnt(0)" ::: "memory");
        __syncthreads();
    }

    // ---- epilogue: finalize the last tile ----
    if (tid < CPB) {
        const int pb = (cnt - 1) & 1;
        const float s = wpart[pb][0][tid] + wpart[pb][1][tid]
                      + wpart[pb][2][tid] + wpart[pb][3][tid];
        out[(swz + (cnt - 1) * GRID) * CPB + tid] = s * (1.0f / (float)K_ROUNDS);
    }
}

extern "C" void kernel_launch(void* const* d_in, const int* in_sizes, int n_in,
                              void* d_out, int out_size, void* d_ws, size_t ws_size,
                              hipStream_t stream) {
    const float* inp     = (const float*)d_in[0];
    const int*   indices = (const int*)d_in[1];
    float*       out     = (float*)d_out;

    bagmax_kernel<<<GRID, BLOCK, 0, stream>>>(inp, indices, out);
}

// Round 13
// 115.563 us; speedup vs baseline: 2.1423x; 1.2696x over previous
//
#include <hip/hip_runtime.h>

// BaggingMaxPool: out[d] = mean_k( max_{r in indices[k,:]} inp[r][d] )
// N=1024 rows, D=100000 cols, K=20 rounds, SELECT_N=256.
//
// Round-13: round-12's async ping-pong structure (persistent 1 block/CU,
// gload_lds staging: zero VGPR, ONE barrier/tile) + the missing TLP.
// Round 12 ran 4 waves = 1 wave/SIMD: every dependent DS latency exposed
// -> 147us. Here BLOCK=640 = 10 waves (2.5/SIMD); wave w owns rounds
// 2w,2w+1 (exact split; total round-instances and shfl count per tile
// unchanged vs rounds 9-12). Staging split across waves 0-7 (8 gload_lds
// each = 128 rows). Double-buffered wpart finalize one tile late.
// LDS: 2x64KB tile + 10.25KB idx + 1.25KB wpart = ~139.8KB -> 1 block/CU.

#define N_ROWS   1024
#define D_COLS   100000
#define K_ROUNDS 20
#define SEL_N    256
#define NIDX     (K_ROUNDS * SEL_N)         // 5120
#define CPB      16                         // cols per tile
#define NT       (D_COLS / CPB)             // 6250 tiles (exact)
#define BLOCK    640                        // 10 waves
#define GRID     256
#define WAVES    10
#define RNDS_PW  (K_ROUNDS / WAVES)         // 2
#define NEG_INF  (-3.402823466e+38f)

// acc = max(acc, lane_shifted_down_by_N(acc)) within each 16-lane row.
template<int CTRL>
__device__ __forceinline__ float dpp_shr_max(float x) {
    const int xi = __float_as_int(x);
    const int sh = __builtin_amdgcn_update_dpp(xi, xi, CTRL, 0xF, 0xF, false);
    return fmaxf(x, __int_as_float(sh));
}
#define ROW_SHR4 0x114
#define ROW_SHR8 0x118

__device__ __forceinline__ void async_cp16(const float* g, float* l) {
    __builtin_amdgcn_global_load_lds(
        (const __attribute__((address_space(1))) unsigned int*)g,
        (__attribute__((address_space(3))) unsigned int*)l,
        16, 0, 0);
}

// Waves 0..7 each stage 128 rows (8 x gload_lds of 16 rows x 16 cols).
// LDS dest wave-uniform; HW adds lane*16B: lane l -> row +(l>>2), unit l&3.
__device__ __forceinline__ void stage_tile(const float* __restrict__ inp,
                                           float* __restrict__ buf,
                                           int colbase, int wave, int lane) {
    if (wave < 8) {
        const int rsub = lane >> 2;             // 0..15
        const int c4   = (lane & 3) * 4;        // 0,4,8,12
        #pragma unroll
        for (int it = 0; it < 8; ++it) {
            const int row = wave * 128 + it * 16 + rsub;
            const float* g = inp + (size_t)row * D_COLS + colbase + c4;   // per-lane
            float* l = &buf[(wave * 128 + it * 16) * CPB];                // uniform
            async_cp16(g, l);
        }
    }
}

__global__ __launch_bounds__(BLOCK, 1) void bagmax_kernel(
    const float* __restrict__ inp,
    const int*   __restrict__ indices,
    float*       __restrict__ out)
{
    __shared__ float tile[2][N_ROWS * CPB];                 // 128 KB
    __shared__ __align__(16) unsigned short sidx[NIDX];     // 10.25 KB
    __shared__ float wpart[2][WAVES][CPB];                  // 1.25 KB

    const int tid  = threadIdx.x;
    const int lane = tid & 63;
    const int wave = tid >> 6;                               // 0..9

    // XCD-chunk swizzle: each XCD's 32 CUs own 32 consecutive col-chunks.
    const int b   = blockIdx.x;
    const int swz = (b & 7) * 32 + (b >> 3);
    const int cnt = (NT - swz + GRID - 1) / GRID;           // 24 or 25 tiles

    // ---- idx preload: coalesced, u16 transposed to [k][g][j] ----
    for (int i = tid; i < NIDX; i += BLOCK) {
        const int p   = i & 255;
        const int dst = (i & ~255) | ((p & 15) << 4) | (p >> 4);
        sidx[dst] = (unsigned short)indices[i];
    }

    // ---- prologue: issue stage of tile 0 ----
    stage_tile(inp, &tile[0][0], swz * CPB, wave, lane);
    asm volatile("s_waitcnt vmcnt(0)" ::: "memory");
    __syncthreads();

    const int g = lane >> 2;            // entry group 0..15
    const int u = lane & 3;             // col unit (cols u*4..u*4+3)

    #pragma unroll 1
    for (int i = 0; i < cnt; ++i) {
        const int cur = i & 1;

        // ---- issue async staging of tile i+1 into the other buffer ----
        if (i + 1 < cnt)
            stage_tile(inp, &tile[cur ^ 1][0], (swz + (i + 1) * GRID) * CPB, wave, lane);

        // ---- finalize tile i-1 (wpart other parity; stable since barrier) ----
        if (i > 0 && tid < CPB) {
            float s = 0.f;
            #pragma unroll
            for (int w = 0; w < WAVES; ++w) s += wpart[cur ^ 1][w][tid];
            out[(swz + (i - 1) * GRID) * CPB + tid] = s * (1.0f / (float)K_ROUNDS);
        }

        // ---- round-major compute on buf[cur]: wave owns rounds 2w,2w+1 ----
        const float* tb = &tile[cur][0];
        float4 rsum = make_float4(0.f, 0.f, 0.f, 0.f);
        #pragma unroll
        for (int kk = 0; kk < RNDS_PW; ++kk) {
            const int k = wave * RNDS_PW + kk;

            const uint4* sp = reinterpret_cast<const uint4*>(&sidx[k * SEL_N + g * 16]);
            const uint4 w0 = sp[0];
            const uint4 w1 = sp[1];
            unsigned int e[16];
            e[0]  = w0.x & 0xFFFFu; e[1]  = w0.x >> 16;
            e[2]  = w0.y & 0xFFFFu; e[3]  = w0.y >> 16;
            e[4]  = w0.z & 0xFFFFu; e[5]  = w0.z >> 16;
            e[6]  = w0.w & 0xFFFFu; e[7]  = w0.w >> 16;
            e[8]  = w1.x & 0xFFFFu; e[9]  = w1.x >> 16;
            e[10] = w1.y & 0xFFFFu; e[11] = w1.y >> 16;
            e[12] = w1.z & 0xFFFFu; e[13] = w1.z >> 16;
            e[14] = w1.w & 0xFFFFu; e[15] = w1.w >> 16;

            float4 a0 = make_float4(NEG_INF, NEG_INF, NEG_INF, NEG_INF);
            float4 a1 = a0;
            #pragma unroll
            for (int j = 0; j < 16; j += 2) {
                const float4 v0 = *reinterpret_cast<const float4*>(&tb[e[j]     * CPB + u * 4]);
                const float4 v1 = *reinterpret_cast<const float4*>(&tb[e[j + 1] * CPB + u * 4]);
                a0.x = fmaxf(a0.x, v0.x); a0.y = fmaxf(a0.y, v0.y);
                a0.z = fmaxf(a0.z, v0.z); a0.w = fmaxf(a0.w, v0.w);
                a1.x = fmaxf(a1.x, v1.x); a1.y = fmaxf(a1.y, v1.y);
                a1.z = fmaxf(a1.z, v1.z); a1.w = fmaxf(a1.w, v1.w);
            }
            float4 acc;
            acc.x = fmaxf(a0.x, a1.x); acc.y = fmaxf(a0.y, a1.y);
            acc.z = fmaxf(a0.z, a1.z); acc.w = fmaxf(a0.w, a1.w);

            // strides 4,8: DPP funnel (VALU pipe) -> valid in lanes 12..15
            acc.x = dpp_shr_max<ROW_SHR4>(acc.x); acc.y = dpp_shr_max<ROW_SHR4>(acc.y);
            acc.z = dpp_shr_max<ROW_SHR4>(acc.z); acc.w = dpp_shr_max<ROW_SHR4>(acc.w);
            acc.x = dpp_shr_max<ROW_SHR8>(acc.x); acc.y = dpp_shr_max<ROW_SHR8>(acc.y);
            acc.z = dpp_shr_max<ROW_SHR8>(acc.z); acc.w = dpp_shr_max<ROW_SHR8>(acc.w);
            // strides 16,32: cross-row (DS pipe)
            acc.x = fmaxf(acc.x, __shfl_xor(acc.x, 16, 64));
            acc.y = fmaxf(acc.y, __shfl_xor(acc.y, 16, 64));
            acc.z = fmaxf(acc.z, __shfl_xor(acc.z, 16, 64));
            acc.w = fmaxf(acc.w, __shfl_xor(acc.w, 16, 64));
            acc.x = fmaxf(acc.x, __shfl_xor(acc.x, 32, 64));
            acc.y = fmaxf(acc.y, __shfl_xor(acc.y, 32, 64));
            acc.z = fmaxf(acc.z, __shfl_xor(acc.z, 32, 64));
            acc.w = fmaxf(acc.w, __shfl_xor(acc.w, 32, 64));

            rsum.x += acc.x; rsum.y += acc.y; rsum.z += acc.z; rsum.w += acc.w;
        }
        if (g == 3)   // lanes 12..15 hold the full reduction; u = lane&3
            *reinterpret_cast<float4*>(&wpart[cur][wave][u * 4]) = rsum;

        // ---- drain prefetch + one barrier per tile ----
        asm volatile("s_waitcnt vmcnt(0)" ::: "memory");
        __syncthreads();
    }

    // ---- epilogue: finalize the last tile ----
    if (tid < CPB) {
        const int pb = (cnt - 1) & 1;
        float s = 0.f;
        #pragma unroll
        for (int w = 0; w < WAVES; ++w) s += wpart[pb][w][tid];
        out[(swz + (cnt - 1) * GRID) * CPB + tid] = s * (1.0f / (float)K_ROUNDS);
    }
}

extern "C" void kernel_launch(void* const* d_in, const int* in_sizes, int n_in,
                              void* d_out, int out_size, void* d_ws, size_t ws_size,
                              hipStream_t stream) {
    const float* inp     = (const float*)d_in[0];
    const int*   indices = (const int*)d_in[1];
    float*       out     = (float*)d_out;

    bagmax_kernel<<<GRID, BLOCK, 0, stream>>>(inp, indices, out);
}